// Round 10
// baseline (153.842 us; speedup 1.0000x reference)
//
#include <hip/hip_runtime.h>
#include <math.h>

// Beam search (8, 512, 32000) fp32, K=3 beams, T=5 top tokens.
// d_out is FLOAT32: tokens (8*512*3) then scores (8*3), concatenated flat.
// Stage 1: per-row top-5 + softmax denom. R10: 1024-thread block per row —
//          4x wider streaming window (16KB/block-iter), 4x fewer concurrent
//          DRAM streams; wave-global top-5 (u64 keys) + warm-up threshold;
//          fully-unrolled 8-batch non-temporal pipeline.
// Stage 2: per-batch serial score scan (2 decision bits/step) + parallel token
//          reconstruction + backpointer suffix-composition. (unchanged)

#define NB 8
#define NL 512
#define NV 32000
#define NT 5
#define NK 3
#define NEG_INF (-__builtin_inff())

typedef unsigned long long ull;
typedef float nfloat4 __attribute__((ext_vector_type(4)));

// Monotone u64 key: larger value wins; ties -> smaller index wins.
__device__ __forceinline__ ull pack_key(float v, int idx) {
  unsigned u = __float_as_uint(v);
  unsigned m = u ^ ((unsigned)((int)u >> 31) | 0x80000000u);
  return ((ull)m << 32) | (ull)(unsigned)(~idx);
}
__device__ __forceinline__ float key_val(ull k) {
  unsigned m = (unsigned)(k >> 32);
  unsigned u = (m & 0x80000000u) ? (m ^ 0x80000000u) : ~m;
  return __uint_as_float(u);
}
__device__ __forceinline__ int key_idx(ull k) { return (int)~(unsigned)k; }

__device__ __forceinline__ float4 ntload(const float4* p) {
  nfloat4 v = __builtin_nontemporal_load((const nfloat4*)p);
  return make_float4(v.x, v.y, v.z, v.w);
}

// maps {0,1,2}->{0,1,2} packed 2 bits each; h = f(g(x)) (g applied first)
__device__ __forceinline__ int compose_map(int f, int g) {
  int h0 = (f >> (2 * (g & 3))) & 3;
  int h1 = (f >> (2 * ((g >> 2) & 3))) & 3;
  int h2 = (f >> (2 * ((g >> 4) & 3))) & 3;
  return h0 | (h1 << 2) | (h2 << 4);
}

// ---------------- Kernel 1: per-(b,l) row: softmax denom + top-5 --------------
// 1024 threads = 16 waves per block; one block per row.
// Row = 8000 float4s: batch0 (warm-up, 1024), batches 1..6 full, batch 7 = 832
// float4s (exactly 13 waves -> wave-uniform guard).
__global__ __launch_bounds__(1024) void k_rowtop5(const float* __restrict__ logits,
                                                  float* __restrict__ lp_out,
                                                  int* __restrict__ idx_out) {
  __shared__ double wsum[16];
  __shared__ float wtv[16 * 5];
  __shared__ int wti[16 * 5];
  __shared__ float mtv[5];
  __shared__ int mti[5];

  const int row = blockIdx.x;
  const int tid = threadIdx.x;
  const int lane = tid & 63;
  const int wv = tid >> 6;

  const float4* __restrict__ x4 = (const float4*)(logits + (size_t)row * NV);

  // wave-global (uniform) sorted top-5 as u64 keys; 0 == -inf sentinel
  ull K0 = 0, K1 = 0, K2 = 0, K3 = 0, K4 = 0;
  double sum = 0.0;

  // sorted-desc cascade insert of a wave-uniform key (new keys are unique)
#define INS_KEY(KEY)                                                           \
  {                                                                            \
    ull key_ = (KEY);                                                          \
    bool b0_ = key_ > K0, b1_ = key_ > K1, b2_ = key_ > K2;                    \
    bool b3_ = key_ > K3, b4_ = key_ > K4;                                     \
    K4 = b4_ ? (b3_ ? K3 : key_) : K4;                                         \
    K3 = b3_ ? (b2_ ? K2 : key_) : K3;                                         \
    K2 = b2_ ? (b1_ ? K1 : key_) : K2;                                         \
    K1 = b1_ ? (b0_ ? K0 : key_) : K1;                                         \
    K0 = b0_ ? key_ : K0;                                                      \
  }

  // ---- warm-up batch 0 (v = tid): exact per-wave top-5 of first 4096 elems --
  float4 f0 = ntload(&x4[tid]);
  {
    float e01 = __expf(f0.x - 4.0f) + __expf(f0.y - 4.0f);
    float e23 = __expf(f0.z - 4.0f) + __expf(f0.w - 4.0f);
    sum += (double)(e01 + e23);
  }
  {
    ull c0 = pack_key(f0.x, tid * 4 + 0);
    ull c1 = pack_key(f0.y, tid * 4 + 1);
    ull c2 = pack_key(f0.z, tid * 4 + 2);
    ull c3 = pack_key(f0.w, tid * 4 + 3);
#pragma unroll
    for (int r = 0; r < 5; ++r) {
      ull a_ = c0 > c1 ? c0 : c1;
      ull b_ = c2 > c3 ? c2 : c3;
      ull wb = a_ > b_ ? a_ : b_;
#pragma unroll
      for (int d = 1; d < 64; d <<= 1) {
        ull o = __shfl_xor(wb, d);
        wb = o > wb ? o : wb;
      }
      INS_KEY(wb);
      c0 = (c0 == wb) ? 0ULL : c0;
      c1 = (c1 == wb) ? 0ULL : c1;
      c2 = (c2 == wb) ? 0ULL : c2;
      c3 = (c3 == wb) ? 0ULL : c3;
    }
  }
  float tv4f = key_val(K4);  // wave-global 5th-best value (real threshold now)

  // slow path for one component: ballot the hitting lanes, broadcast-insert
#define SLOW(CVAL, E)                                                          \
  {                                                                            \
    ull mm_ = __ballot((CVAL) >= tv4f);                                        \
    while (mm_) {                                                              \
      int l_ = __ffsll((unsigned long long)mm_) - 1;                           \
      mm_ &= mm_ - 1;                                                          \
      float bv_ = __shfl((CVAL), l_);                                          \
      int bidx_ = (vbase + l_) * 4 + (E);                                      \
      INS_KEY(pack_key(bv_, bidx_));                                           \
    }                                                                          \
  }

  // process one float4 at batch index KB
#define COMP(Q, KB)                                                            \
  {                                                                            \
    float ex = __expf((Q).x - 4.0f), ey = __expf((Q).y - 4.0f);                \
    float ez = __expf((Q).z - 4.0f), ew = __expf((Q).w - 4.0f);                \
    sum += (double)((ex + ey) + (ez + ew));                                    \
    float m4 = fmaxf(fmaxf((Q).x, (Q).y), fmaxf((Q).z, (Q).w));                \
    if (__ballot(m4 >= tv4f)) {                                                \
      const int vbase = (tid - lane) + 1024 * (KB);                            \
      SLOW((Q).x, 0)                                                           \
      SLOW((Q).y, 1)                                                           \
      SLOW((Q).z, 2)                                                           \
      SLOW((Q).w, 3)                                                           \
      tv4f = key_val(K4);                                                      \
    }                                                                          \
  }

  // guarded load: clamp OOB to a safe in-row address (never consumed)
#define GLOAD(Q, KB)                                                           \
  {                                                                            \
    int vv = tid + 1024 * (KB);                                                \
    vv = (vv < NV / 4) ? vv : tid;                                             \
    (Q) = ntload(&x4[vv]);                                                     \
  }

  // ---- fully-unrolled 4-deep pipeline over batches 1..7 ----
  float4 q0, q1, q2, q3;
  GLOAD(q0, 1) GLOAD(q1, 2) GLOAD(q2, 3) GLOAD(q3, 4)
  COMP(q0, 1) GLOAD(q0, 5)
  COMP(q1, 2) GLOAD(q1, 6)
  COMP(q2, 3) GLOAD(q2, 7)
  COMP(q3, 4)
  COMP(q0, 5)
  COMP(q1, 6)
  if (tid < 832) {  // batch 7: waves 0..12 fully active (wave-uniform)
    COMP(q2, 7)
  }
#undef GLOAD
#undef COMP
#undef SLOW
#undef INS_KEY

  // wave sum reduce (double)
#pragma unroll
  for (int d = 1; d < 64; d <<= 1) sum += __shfl_xor(sum, d);
  if (lane == 0) wsum[wv] = sum;

  // each wave publishes its sorted top-5 (uniform registers; lane k writes k)
  if (lane < 5) {
    ull myk = (lane == 0) ? K0 : (lane == 1) ? K1 : (lane == 2) ? K2
            : (lane == 3) ? K3 : K4;
    wtv[wv * 5 + lane] = key_val(myk);
    wti[wv * 5 + lane] = key_idx(myk);
  }
  __syncthreads();

  // wave 0: merge 16 sorted lists by 5 rounds of parallel argmax-pop.
  // Lane i (i<16) tracks the head of list i in a register; keys are unique.
  if (wv == 0) {
    int head = 0;
#pragma unroll
    for (int r = 0; r < 5; ++r) {
      ull hk = 0;
      if (lane < 16 && head < 5) {
        hk = pack_key(wtv[lane * 5 + head], wti[lane * 5 + head]);
      }
      ull mx = hk;
#pragma unroll
      for (int d = 1; d < 64; d <<= 1) {
        ull o = __shfl_xor(mx, d);
        mx = o > mx ? o : mx;
      }
      if (hk == mx) head++;  // unique winner advances
      if (lane == 0) { mtv[r] = key_val(mx); mti[r] = key_idx(mx); }
    }
  }
  __syncthreads();

  if (tid < 5) {
    double S = wsum[0];
#pragma unroll
    for (int i = 1; i < 16; ++i) S += wsum[i];
    // near-correctly-rounded lp: double exp / double S / double log -> fp32
    double p = exp((double)mtv[tid] - 4.0) / S;
    float lp = (float)log(p + 2.220446049250313e-16);
    lp_out[row * 5 + tid] = lp;
    idx_out[row * 5 + tid] = mti[tid];
  }
}

// ---------------- Kernel 2: per-batch beam scan + backtrace -------------------
// Frontier pruning (rows: beams desc s0>=s1>=s2, cols: lp desc l0>=l1>=l2):
//   cell (k,t) has (k+1)(t+1)-1 strict-rank dominators -> only
//   {c00,c01,c02,c10,c20} can reach top-3. top1 = c00 always.
//   t1 = better(c01[flat1], c10[flat5]); if t1==c01: t2 = better(c02[2],c10[5])
//   else t2 = better(c01[1], c20[10]). In each compare the left operand has the
//   smaller flat index, so float '>=' reproduces top_k tie-breaking exactly.
__global__ __launch_bounds__(64) void k_beamscan(const float* __restrict__ lp_in,
                                                 const int* __restrict__ idx_in,
                                                 float* __restrict__ out) {
  __shared__ float lpc[(NL + 8) * 3];       // compacted l0,l1,l2 per step + pad
  __shared__ int idxL[NL * NT];
  __shared__ unsigned char selb[NL / 4];    // 2 decision bits per step

  const int b = blockIdx.x;
  const int tid = threadIdx.x;

  // stage idx (vectorized) and compacted lp triples
  const int4* ip = (const int4*)(idx_in + (size_t)b * NL * NT);
  for (int i = tid; i < NL * NT / 4; i += 64) ((int4*)idxL)[i] = ip[i];
  const float* lpb = lp_in + (size_t)b * NL * NT;
  for (int i = tid; i < NL; i += 64) {
    lpc[i * 3 + 0] = lpb[i * 5 + 0];
    lpc[i * 3 + 1] = lpb[i * 5 + 1];
    lpc[i * 3 + 2] = lpb[i * 5 + 2];
  }
  if (tid < 24) lpc[NL * 3 + tid] = 0.f;  // prefetch overrun pad
  __syncthreads();

  if (tid == 0) {
    float s0 = 0.f, s1 = NEG_INF, s2 = NEG_INF;
    float lA0 = lpc[0], lA1 = lpc[1],  lA2 = lpc[2];
    float lB0 = lpc[3], lB1 = lpc[4],  lB2 = lpc[5];
    float lC0 = lpc[6], lC1 = lpc[7],  lC2 = lpc[8];
    float lD0 = lpc[9], lD1 = lpc[10], lD2 = lpc[11];
    for (int t = 0; t < NL; t += 4) {
      unsigned byte_ = 0;
      int pfb = (t + 4) * 3;
#define STEP(L0, L1, L2, SH, PF)                                               \
      {                                                                        \
        float c00 = s0 + L0, c01 = s0 + L1, c02 = s0 + L2;                     \
        float c10 = s1 + L0, c20 = s2 + L0;                                    \
        bool a_ = c01 >= c10;                                                  \
        float xv = a_ ? c02 : c01;                                             \
        float yv = a_ ? c10 : c20;                                             \
        bool sb_ = xv >= yv;                                                   \
        s0 = c00;                                                              \
        s1 = a_ ? c01 : c10;                                                   \
        s2 = sb_ ? xv : yv;                                                    \
        byte_ |= ((unsigned)a_ | ((unsigned)sb_ << 1)) << (SH);                \
        PF                                                                     \
      }
      STEP(lA0, lA1, lA2, 0, { lA0 = lpc[pfb + 0]; lA1 = lpc[pfb + 1];  lA2 = lpc[pfb + 2]; })
      STEP(lB0, lB1, lB2, 2, { lB0 = lpc[pfb + 3]; lB1 = lpc[pfb + 4];  lB2 = lpc[pfb + 5]; })
      STEP(lC0, lC1, lC2, 4, { lC0 = lpc[pfb + 6]; lC1 = lpc[pfb + 7];  lC2 = lpc[pfb + 8]; })
      STEP(lD0, lD1, lD2, 6, { lD0 = lpc[pfb + 9]; lD1 = lpc[pfb + 10]; lD2 = lpc[pfb + 11]; })
#undef STEP
      selb[t >> 2] = (unsigned char)byte_;
    }
    out[NB * NL * NK + b * NK + 0] = s0;
    out[NB * NL * NK + b * NK + 1] = s1;
    out[NB * NL * NK + b * NK + 2] = s2;
  }
  __syncthreads();

  // decode this lane's 8 steps: tokens + parents from decision bits
  const int base = tid * 8;
  unsigned bits0 = selb[(base >> 2) + 0];
  unsigned bits1 = selb[(base >> 2) + 1];
  int e0[8], e1[8], e2[8];  // token | parent<<20
#pragma unroll
  for (int k = 0; k < 8; ++k) {
    int t = base + k;
    unsigned bb = ((k < 4) ? (bits0 >> (2 * k)) : (bits1 >> (2 * (k - 4)))) & 3u;
    int a_ = bb & 1, sb_ = (bb >> 1) & 1;
    int q1 = a_ ? 1 : 0, p1 = a_ ? 0 : 1;
    int q2 = a_ ? (sb_ ? 2 : 0) : (sb_ ? 1 : 0);
    int p2 = a_ ? (sb_ ? 0 : 1) : (sb_ ? 0 : 2);
    e0[k] = idxL[t * NT + 0];
    e1[k] = idxL[t * NT + q1] | (p1 << 20);
    e2[k] = idxL[t * NT + q2] | (p2 << 20);
  }

  // parallel backtrace: suffix composition of parent maps g_t over t
  const int ID3 = 0 | (1 << 2) | (2 << 4);
  int P = ID3;
#pragma unroll
  for (int k = 7; k >= 0; --k) {  // local product, highest t applied first
    int g = (e0[k] >> 20) | ((e1[k] >> 20) << 2) | ((e2[k] >> 20) << 4);
    P = compose_map(g, P);
  }
  int X = P;  // inclusive suffix scan across lanes
#pragma unroll
  for (int d = 1; d < 64; d <<= 1) {
    int o = __shfl_down(X, d);
    if (tid + d < 64) X = compose_map(X, o);
  }
  int E = __shfl_down(X, 1);  // exclusive suffix = composition over t > base+7
  if (tid == 63) E = ID3;

  int R = E;  // map_t for t = base+7
  const int ob = b * NL * NK;
#pragma unroll
  for (int k = 7; k >= 0; --k) {
    int t = base + k;
    int m0 = R & 3, m1 = (R >> 2) & 3, m2 = (R >> 4) & 3;
    int tok0 = (m0 == 0 ? e0[k] : m0 == 1 ? e1[k] : e2[k]) & 0xFFFFF;
    int tok1 = (m1 == 0 ? e0[k] : m1 == 1 ? e1[k] : e2[k]) & 0xFFFFF;
    int tok2 = (m2 == 0 ? e0[k] : m2 == 1 ? e1[k] : e2[k]) & 0xFFFFF;
    out[ob + t * 3 + 0] = (float)tok0;
    out[ob + t * 3 + 1] = (float)tok1;
    out[ob + t * 3 + 2] = (float)tok2;
    int g = (e0[k] >> 20) | ((e1[k] >> 20) << 2) | ((e2[k] >> 20) << 4);
    R = compose_map(g, R);
  }
}

extern "C" void kernel_launch(void* const* d_in, const int* in_sizes, int n_in,
                              void* d_out, int out_size, void* d_ws, size_t ws_size,
                              hipStream_t stream) {
  const float* logits = (const float*)d_in[0];
  float* lp = (float*)d_ws;
  int* idx = (int*)((char*)d_ws + (size_t)NB * NL * NT * sizeof(float));
  float* out = (float*)d_out;

  hipLaunchKernelGGL(k_rowtop5, dim3(NB * NL), dim3(1024), 0, stream, logits, lp, idx);
  hipLaunchKernelGGL(k_beamscan, dim3(NB), dim3(64), 0, stream, lp, idx, out);
}

// Round 11
// 121.517 us; speedup vs baseline: 1.2660x; 1.2660x over previous
//
#include <hip/hip_runtime.h>
#include <math.h>

// Beam search (8, 512, 32000) fp32, K=3 beams, T=5 top tokens.
// d_out is FLOAT32: tokens (8*512*3) then scores (8*3), concatenated flat.
// Stage 1: per-row (4096 rows) softmax denom + top-5 -> ws.
//          Wave-global top-5 (uniform u64 keys), warm-up-initialized threshold,
//          4-deep software-pipelined NON-TEMPORAL float4 loads.
//          (R11: exact revert to the best-measured R9 configuration, 121.6us.)
// Stage 2: per-batch serial score scan (2 decision bits/step) + parallel token
//          reconstruction + backpointer suffix-composition. (unchanged)

#define NB 8
#define NL 512
#define NV 32000
#define NT 5
#define NK 3
#define NEG_INF (-__builtin_inff())

typedef unsigned long long ull;
typedef float nfloat4 __attribute__((ext_vector_type(4)));

// Monotone u64 key: larger value wins; ties -> smaller index wins.
__device__ __forceinline__ ull pack_key(float v, int idx) {
  unsigned u = __float_as_uint(v);
  unsigned m = u ^ ((unsigned)((int)u >> 31) | 0x80000000u);
  return ((ull)m << 32) | (ull)(unsigned)(~idx);
}
__device__ __forceinline__ float key_val(ull k) {
  unsigned m = (unsigned)(k >> 32);
  unsigned u = (m & 0x80000000u) ? (m ^ 0x80000000u) : ~m;
  return __uint_as_float(u);
}
__device__ __forceinline__ int key_idx(ull k) { return (int)~(unsigned)k; }

__device__ __forceinline__ float4 ntload(const float4* p) {
  nfloat4 v = __builtin_nontemporal_load((const nfloat4*)p);
  return make_float4(v.x, v.y, v.z, v.w);
}

// maps {0,1,2}->{0,1,2} packed 2 bits each; h = f(g(x)) (g applied first)
__device__ __forceinline__ int compose_map(int f, int g) {
  int h0 = (f >> (2 * (g & 3))) & 3;
  int h1 = (f >> (2 * ((g >> 2) & 3))) & 3;
  int h2 = (f >> (2 * ((g >> 4) & 3))) & 3;
  return h0 | (h1 << 2) | (h2 << 4);
}

// ---------------- Kernel 1: per-(b,l) row: softmax denom + top-5 --------------
__global__ __launch_bounds__(256) void k_rowtop5(const float* __restrict__ logits,
                                                 float* __restrict__ lp_out,
                                                 int* __restrict__ idx_out) {
  __shared__ double wsum[4];
  __shared__ float wtv[4 * 5];
  __shared__ int wti[4 * 5];
  __shared__ float mtv[5];
  __shared__ int mti[5];

  const int row = blockIdx.x;
  const int tid = threadIdx.x;
  const int lane = tid & 63;
  const int wv = tid >> 6;

  const float4* __restrict__ x4 = (const float4*)(logits + (size_t)row * NV);

  // wave-global (uniform) sorted top-5 as u64 keys; 0 == -inf sentinel
  ull K0 = 0, K1 = 0, K2 = 0, K3 = 0, K4 = 0;
  double sum = 0.0;

  // sorted-desc cascade insert of a wave-uniform key (new keys are unique)
#define INS_KEY(KEY)                                                           \
  {                                                                            \
    ull key_ = (KEY);                                                          \
    bool b0_ = key_ > K0, b1_ = key_ > K1, b2_ = key_ > K2;                    \
    bool b3_ = key_ > K3, b4_ = key_ > K4;                                     \
    K4 = b4_ ? (b3_ ? K3 : key_) : K4;                                         \
    K3 = b3_ ? (b2_ ? K2 : key_) : K3;                                         \
    K2 = b2_ ? (b1_ ? K1 : key_) : K2;                                         \
    K1 = b1_ ? (b0_ ? K0 : key_) : K1;                                         \
    K0 = b0_ ? key_ : K0;                                                      \
  }

  // ---- warm-up batch (v = tid): exact top-5 of first 1024 elements ----
  float4 f0 = ntload(&x4[tid]);
  {
    float e01 = __expf(f0.x - 4.0f) + __expf(f0.y - 4.0f);
    float e23 = __expf(f0.z - 4.0f) + __expf(f0.w - 4.0f);
    sum += (double)(e01 + e23);
  }
  {
    ull c0 = pack_key(f0.x, tid * 4 + 0);
    ull c1 = pack_key(f0.y, tid * 4 + 1);
    ull c2 = pack_key(f0.z, tid * 4 + 2);
    ull c3 = pack_key(f0.w, tid * 4 + 3);
#pragma unroll
    for (int r = 0; r < 5; ++r) {
      ull a_ = c0 > c1 ? c0 : c1;
      ull b_ = c2 > c3 ? c2 : c3;
      ull wb = a_ > b_ ? a_ : b_;
#pragma unroll
      for (int d = 1; d < 64; d <<= 1) {
        ull o = __shfl_xor(wb, d);
        wb = o > wb ? o : wb;
      }
      INS_KEY(wb);
      c0 = (c0 == wb) ? 0ULL : c0;
      c1 = (c1 == wb) ? 0ULL : c1;
      c2 = (c2 == wb) ? 0ULL : c2;
      c3 = (c3 == wb) ? 0ULL : c3;
    }
  }
  float tv4f = key_val(K4);  // wave-global 5th-best value (real threshold now)

  // slow path for one component: ballot the hitting lanes, broadcast-insert
#define SLOW(CVAL, E)                                                          \
  {                                                                            \
    ull mm_ = __ballot((CVAL) >= tv4f);                                        \
    while (mm_) {                                                              \
      int l_ = __ffsll((unsigned long long)mm_) - 1;                           \
      mm_ &= mm_ - 1;                                                          \
      float bv_ = __shfl((CVAL), l_);                                          \
      int bidx_ = (vbase + l_) * 4 + (E);                                      \
      INS_KEY(pack_key(bv_, bidx_));                                           \
    }                                                                          \
  }

  // process one float4 at batch index KB (sum order identical to R6/R7 runs)
#define COMP(Q, KB)                                                            \
  {                                                                            \
    float ex = __expf((Q).x - 4.0f), ey = __expf((Q).y - 4.0f);                \
    float ez = __expf((Q).z - 4.0f), ew = __expf((Q).w - 4.0f);                \
    sum += (double)((ex + ey) + (ez + ew));                                    \
    float m4 = fmaxf(fmaxf((Q).x, (Q).y), fmaxf((Q).z, (Q).w));                \
    if (__ballot(m4 >= tv4f)) {                                                \
      const int vbase = (tid - lane) + 256 * (KB);                             \
      SLOW((Q).x, 0)                                                           \
      SLOW((Q).y, 1)                                                           \
      SLOW((Q).z, 2)                                                           \
      SLOW((Q).w, 3)                                                           \
      tv4f = key_val(K4);                                                      \
    }                                                                          \
  }

  // guarded load: clamp OOB batch to a safe in-row address (never consumed)
#define GLOAD(Q, KB)                                                           \
  {                                                                            \
    int vv = tid + 256 * (KB);                                                 \
    vv = (vv < NV / 4) ? vv : tid;                                             \
    (Q) = ntload(&x4[vv]);                                                     \
  }

  // ---- main loop: 4-deep software pipeline over batches 1..31 ----
  // batches: 1..28 pipelined; 29,30 epilogue (all threads); 31 wave-0 only.
  float4 q0, q1, q2, q3;
  GLOAD(q0, 1) GLOAD(q1, 2) GLOAD(q2, 3) GLOAD(q3, 4)
  for (int k = 1; k <= 25; k += 4) {
    COMP(q0, k)     GLOAD(q0, k + 4)
    COMP(q1, k + 1) GLOAD(q1, k + 5)
    COMP(q2, k + 2) GLOAD(q2, k + 6)
    COMP(q3, k + 3) GLOAD(q3, k + 7)
  }
  COMP(q0, 29)
  COMP(q1, 30)
  if (tid < 64) {  // wave-uniform: batch 31 exists only for threads 0..63
    COMP(q2, 31)
  }
#undef GLOAD
#undef COMP
#undef SLOW
#undef INS_KEY

  // wave sum reduce (double)
#pragma unroll
  for (int d = 1; d < 64; d <<= 1) sum += __shfl_xor(sum, d);
  if (lane == 0) wsum[wv] = sum;

  // each wave publishes its sorted top-5 (uniform registers; lane k writes k)
  if (lane < 5) {
    ull myk = (lane == 0) ? K0 : (lane == 1) ? K1 : (lane == 2) ? K2
            : (lane == 3) ? K3 : K4;
    wtv[wv * 5 + lane] = key_val(myk);
    wti[wv * 5 + lane] = key_idx(myk);
  }
  __syncthreads();

  // thread 0: 4-way merge of sorted lists (val desc, idx asc tie-break)
  if (tid == 0) {
    int h0 = 0, h1 = 0, h2 = 0, h3 = 0;
#pragma unroll
    for (int k = 0; k < 5; ++k) {
      float v0 = (h0 < 5) ? wtv[0 + h0] : NEG_INF;  int j0 = (h0 < 5) ? wti[0 + h0] : 0x7fffffff;
      float v1 = (h1 < 5) ? wtv[5 + h1] : NEG_INF;  int j1 = (h1 < 5) ? wti[5 + h1] : 0x7fffffff;
      float v2 = (h2 < 5) ? wtv[10 + h2] : NEG_INF; int j2 = (h2 < 5) ? wti[10 + h2] : 0x7fffffff;
      float v3 = (h3 < 5) ? wtv[15 + h3] : NEG_INF; int j3 = (h3 < 5) ? wti[15 + h3] : 0x7fffffff;
      float bv = v0; int bj = j0; int bs = 0;
      if (v1 > bv || (v1 == bv && j1 < bj)) { bv = v1; bj = j1; bs = 1; }
      if (v2 > bv || (v2 == bv && j2 < bj)) { bv = v2; bj = j2; bs = 2; }
      if (v3 > bv || (v3 == bv && j3 < bj)) { bv = v3; bj = j3; bs = 3; }
      mtv[k] = bv; mti[k] = bj;
      h0 += (bs == 0); h1 += (bs == 1); h2 += (bs == 2); h3 += (bs == 3);
    }
  }
  __syncthreads();

  if (tid < 5) {
    const double S = wsum[0] + wsum[1] + wsum[2] + wsum[3];
    // near-correctly-rounded lp: double exp / double S / double log -> fp32
    double p = exp((double)mtv[tid] - 4.0) / S;
    float lp = (float)log(p + 2.220446049250313e-16);
    lp_out[row * 5 + tid] = lp;
    idx_out[row * 5 + tid] = mti[tid];
  }
}

// ---------------- Kernel 2: per-batch beam scan + backtrace -------------------
// Frontier pruning (rows: beams desc s0>=s1>=s2, cols: lp desc l0>=l1>=l2):
//   cell (k,t) has (k+1)(t+1)-1 strict-rank dominators -> only
//   {c00,c01,c02,c10,c20} can reach top-3. top1 = c00 always.
//   t1 = better(c01[flat1], c10[flat5]); if t1==c01: t2 = better(c02[2],c10[5])
//   else t2 = better(c01[1], c20[10]). In each compare the left operand has the
//   smaller flat index, so float '>=' reproduces top_k tie-breaking exactly.
__global__ __launch_bounds__(64) void k_beamscan(const float* __restrict__ lp_in,
                                                 const int* __restrict__ idx_in,
                                                 float* __restrict__ out) {
  __shared__ float lpc[(NL + 8) * 3];       // compacted l0,l1,l2 per step + pad
  __shared__ int idxL[NL * NT];
  __shared__ unsigned char selb[NL / 4];    // 2 decision bits per step

  const int b = blockIdx.x;
  const int tid = threadIdx.x;

  // stage idx (vectorized) and compacted lp triples
  const int4* ip = (const int4*)(idx_in + (size_t)b * NL * NT);
  for (int i = tid; i < NL * NT / 4; i += 64) ((int4*)idxL)[i] = ip[i];
  const float* lpb = lp_in + (size_t)b * NL * NT;
  for (int i = tid; i < NL; i += 64) {
    lpc[i * 3 + 0] = lpb[i * 5 + 0];
    lpc[i * 3 + 1] = lpb[i * 5 + 1];
    lpc[i * 3 + 2] = lpb[i * 5 + 2];
  }
  if (tid < 24) lpc[NL * 3 + tid] = 0.f;  // prefetch overrun pad
  __syncthreads();

  if (tid == 0) {
    float s0 = 0.f, s1 = NEG_INF, s2 = NEG_INF;
    float lA0 = lpc[0], lA1 = lpc[1],  lA2 = lpc[2];
    float lB0 = lpc[3], lB1 = lpc[4],  lB2 = lpc[5];
    float lC0 = lpc[6], lC1 = lpc[7],  lC2 = lpc[8];
    float lD0 = lpc[9], lD1 = lpc[10], lD2 = lpc[11];
    for (int t = 0; t < NL; t += 4) {
      unsigned byte_ = 0;
      int pfb = (t + 4) * 3;
#define STEP(L0, L1, L2, SH, PF)                                               \
      {                                                                        \
        float c00 = s0 + L0, c01 = s0 + L1, c02 = s0 + L2;                     \
        float c10 = s1 + L0, c20 = s2 + L0;                                    \
        bool a_ = c01 >= c10;                                                  \
        float xv = a_ ? c02 : c01;                                             \
        float yv = a_ ? c10 : c20;                                             \
        bool sb_ = xv >= yv;                                                   \
        s0 = c00;                                                              \
        s1 = a_ ? c01 : c10;                                                   \
        s2 = sb_ ? xv : yv;                                                    \
        byte_ |= ((unsigned)a_ | ((unsigned)sb_ << 1)) << (SH);                \
        PF                                                                     \
      }
      STEP(lA0, lA1, lA2, 0, { lA0 = lpc[pfb + 0]; lA1 = lpc[pfb + 1];  lA2 = lpc[pfb + 2]; })
      STEP(lB0, lB1, lB2, 2, { lB0 = lpc[pfb + 3]; lB1 = lpc[pfb + 4];  lB2 = lpc[pfb + 5]; })
      STEP(lC0, lC1, lC2, 4, { lC0 = lpc[pfb + 6]; lC1 = lpc[pfb + 7];  lC2 = lpc[pfb + 8]; })
      STEP(lD0, lD1, lD2, 6, { lD0 = lpc[pfb + 9]; lD1 = lpc[pfb + 10]; lD2 = lpc[pfb + 11]; })
#undef STEP
      selb[t >> 2] = (unsigned char)byte_;
    }
    out[NB * NL * NK + b * NK + 0] = s0;
    out[NB * NL * NK + b * NK + 1] = s1;
    out[NB * NL * NK + b * NK + 2] = s2;
  }
  __syncthreads();

  // decode this lane's 8 steps: tokens + parents from decision bits
  const int base = tid * 8;
  unsigned bits0 = selb[(base >> 2) + 0];
  unsigned bits1 = selb[(base >> 2) + 1];
  int e0[8], e1[8], e2[8];  // token | parent<<20
#pragma unroll
  for (int k = 0; k < 8; ++k) {
    int t = base + k;
    unsigned bb = ((k < 4) ? (bits0 >> (2 * k)) : (bits1 >> (2 * (k - 4)))) & 3u;
    int a_ = bb & 1, sb_ = (bb >> 1) & 1;
    int q1 = a_ ? 1 : 0, p1 = a_ ? 0 : 1;
    int q2 = a_ ? (sb_ ? 2 : 0) : (sb_ ? 1 : 0);
    int p2 = a_ ? (sb_ ? 0 : 1) : (sb_ ? 0 : 2);
    e0[k] = idxL[t * NT + 0];
    e1[k] = idxL[t * NT + q1] | (p1 << 20);
    e2[k] = idxL[t * NT + q2] | (p2 << 20);
  }

  // parallel backtrace: suffix composition of parent maps g_t over t
  const int ID3 = 0 | (1 << 2) | (2 << 4);
  int P = ID3;
#pragma unroll
  for (int k = 7; k >= 0; --k) {  // local product, highest t applied first
    int g = (e0[k] >> 20) | ((e1[k] >> 20) << 2) | ((e2[k] >> 20) << 4);
    P = compose_map(g, P);
  }
  int X = P;  // inclusive suffix scan across lanes
#pragma unroll
  for (int d = 1; d < 64; d <<= 1) {
    int o = __shfl_down(X, d);
    if (tid + d < 64) X = compose_map(X, o);
  }
  int E = __shfl_down(X, 1);  // exclusive suffix = composition over t > base+7
  if (tid == 63) E = ID3;

  int R = E;  // map_t for t = base+7
  const int ob = b * NL * NK;
#pragma unroll
  for (int k = 7; k >= 0; --k) {
    int t = base + k;
    int m0 = R & 3, m1 = (R >> 2) & 3, m2 = (R >> 4) & 3;
    int tok0 = (m0 == 0 ? e0[k] : m0 == 1 ? e1[k] : e2[k]) & 0xFFFFF;
    int tok1 = (m1 == 0 ? e0[k] : m1 == 1 ? e1[k] : e2[k]) & 0xFFFFF;
    int tok2 = (m2 == 0 ? e0[k] : m2 == 1 ? e1[k] : e2[k]) & 0xFFFFF;
    out[ob + t * 3 + 0] = (float)tok0;
    out[ob + t * 3 + 1] = (float)tok1;
    out[ob + t * 3 + 2] = (float)tok2;
    int g = (e0[k] >> 20) | ((e1[k] >> 20) << 2) | ((e2[k] >> 20) << 4);
    R = compose_map(g, R);
  }
}

extern "C" void kernel_launch(void* const* d_in, const int* in_sizes, int n_in,
                              void* d_out, int out_size, void* d_ws, size_t ws_size,
                              hipStream_t stream) {
  const float* logits = (const float*)d_in[0];
  float* lp = (float*)d_ws;
  int* idx = (int*)((char*)d_ws + (size_t)NB * NL * NT * sizeof(float));
  float* out = (float*)d_out;

  hipLaunchKernelGGL(k_rowtop5, dim3(NB * NL), dim3(256), 0, stream, logits, lp, idx);
  hipLaunchKernelGGL(k_beamscan, dim3(NB), dim3(64), 0, stream, lp, idx, out);
}